// Round 11
// baseline (136.981 us; speedup 1.0000x reference)
//
#include <hip/hip_runtime.h>
#include <math.h>

// Chamfer distance, B=4, N=M=8192, fp32.
// Output layout (flat float32): dist1[B*N], dist2[B*M], idx1[B*N] (as float),
// idx2[B*M] (as float).
//
// R10: R9's proven main body (79 us, absmax 0) + finalize moved into the SAME
// dispatch as 16 dedicated finalizer blocks (extra blockIdx.y plane) that
// spin on a release/acquire worker counter, then unpack pp -> out. Worker
// path unchanged except a tail { __syncthreads; lane0 release-increment }.
// Counter inits to 0xFFFFFFFF via the same 0xFF memset as pp; finalizers
// wait for 0xFFFFFFFF + nworkers (unsigned wrap). 2 graph nodes total
// (memset + kernel) vs R9's 3 — per-node cost measured ~10-12 us.
//
// Semantics (unchanged): d = fmaf(dx,dx,fmaf(dy,dy,dz*dz)); group-of-8 min
// tree, strict < keeps earliest group; winner resolved by deterministic
// recompute (bitwise-identical d), descending scan -> smallest index; u64
// atomicMin of (dist_bits<<32|idx) tie-breaks to lower global index ==
// np.argmin first-occurrence. absmax 0 measured R5-R9.

#define QPT 4         // queries per thread
#define BLK 256       // threads per block
#define QPB (QPT*BLK) // queries per block = 1024

__global__ __launch_bounds__(256, 4) void chamfer_main(
    const float* __restrict__ xyz1, const float* __restrict__ xyz2,
    unsigned long long* __restrict__ pp, unsigned* __restrict__ cnt,
    float* __restrict__ out, int N, int M, int B, int S, int C)
{
    // ---------------- finalizer plane ----------------
    if (blockIdx.y == (unsigned)(B * S)) {
        const unsigned nworkers = gridDim.x * (gridDim.y - 1) * gridDim.z;
        const unsigned target = 0xFFFFFFFFu + nworkers;  // unsigned wrap
        while (__hip_atomic_load(cnt, __ATOMIC_ACQUIRE,
                                 __HIP_MEMORY_SCOPE_AGENT) != target)
            __builtin_amdgcn_s_sleep(16);

        const int fid  = blockIdx.x + gridDim.x * blockIdx.z;  // [0, 2*nqt)
        const int nfin = 2 * gridDim.x;
        const int perDir0 = B * N;
        const int totalOut = B * N + B * M;
        for (int gid = fid * BLK + threadIdx.x; gid < totalOut;
             gid += nfin * BLK) {
            int dir, rem;
            if (gid < perDir0) { dir = 0; rem = gid; }
            else               { dir = 1; rem = gid - perDir0; }
            const int Nq = dir ? M : N;
            unsigned long long v = __hip_atomic_load(
                &pp[(size_t)(dir * B) * Nq + rem],
                __ATOMIC_RELAXED, __HIP_MEMORY_SCOPE_AGENT);
            float* dist_out = out + (dir ? (size_t)B * N : 0);
            float* idx_out  = out + (size_t)B * N + (size_t)B * M
                                  + (dir ? (size_t)B * N : 0);
            dist_out[rem] = __uint_as_float((unsigned)(v >> 32));
            idx_out[rem]  = (float)(unsigned)(v & 0xffffffffu);
        }
        return;
    }

    // ---------------- worker plane (R9 body, unchanged) ----------------
    const int dir = blockIdx.z;          // 0: xyz1->xyz2, 1: xyz2->xyz1
    const float* q = dir ? xyz2 : xyz1;  // query cloud
    const float* r = dir ? xyz1 : xyz2;  // reference cloud
    const int Nq = dir ? M : N;
    const int Nr = dir ? N : M;
    const int b     = blockIdx.y / S;
    const int split = blockIdx.y % S;
    const int base  = split * C;         // this block's ref-index range [base, base+C)

    extern __shared__ float s[];         // C*3 floats

    // cooperative vectorized tile load (C%8==0 -> byte count divisible by 16)
    {
        const float4* gv = (const float4*)(r + ((size_t)b * Nr + base) * 3);
        float4* sv = (float4*)s;
        const int elems4 = C * 3 / 4;
        for (int t = threadIdx.x; t < elems4; t += BLK) sv[t] = gv[t];
    }
    __syncthreads();

    // load 4 query points (stride-BLK within the block's query window)
    float qx[QPT], qy[QPT], qz[QPT];
    int qi[QPT];
    bool qv[QPT];
#pragma unroll
    for (int k = 0; k < QPT; ++k) {
        qi[k] = blockIdx.x * QPB + k * BLK + threadIdx.x;
        qv[k] = qi[k] < Nq;
        const float* qp = q + ((size_t)b * Nq + (qv[k] ? qi[k] : 0)) * 3;
        qx[k] = qp[0]; qy[k] = qp[1]; qz[k] = qp[2];
    }

    // per-query running min + winning 8-group id
    float bd[QPT];
    int   gi[QPT];
#pragma unroll
    for (int k = 0; k < QPT; ++k) { bd[k] = INFINITY; gi[k] = 0; }

    const float4* sv = (const float4*)s;
    const int iters = C / 8;
    for (int j8 = 0; j8 < iters; ++j8) {
        // 24 floats = 8 ref points; all lanes same address -> LDS broadcast
        float4 f0 = sv[6 * j8 + 0];
        float4 f1 = sv[6 * j8 + 1];
        float4 f2 = sv[6 * j8 + 2];
        float4 f3 = sv[6 * j8 + 3];
        float4 f4 = sv[6 * j8 + 4];
        float4 f5 = sv[6 * j8 + 5];
        float px[8] = { f0.x, f0.w, f1.z, f2.y, f3.x, f3.w, f4.z, f5.y };
        float py[8] = { f0.y, f1.x, f1.w, f2.z, f3.y, f4.x, f4.w, f5.z };
        float pz[8] = { f0.z, f1.y, f2.x, f2.w, f3.z, f4.y, f5.x, f5.w };
#pragma unroll
        for (int k = 0; k < QPT; ++k) {
            float d[8];
#pragma unroll
            for (int p = 0; p < 8; ++p) {
                float dx = qx[k] - px[p];
                float dy = qy[k] - py[p];
                float dz = qz[k] - pz[p];
                d[p] = fmaf(dx, dx, fmaf(dy, dy, dz * dz));
            }
            // min-of-8 tree (compiler folds fminf pairs/triples into v_min3)
            float m01 = fminf(d[0], d[1]);
            float m23 = fminf(d[2], d[3]);
            float m45 = fminf(d[4], d[5]);
            float m67 = fminf(d[6], d[7]);
            float m = fminf(fminf(m01, m23), fminf(m45, m67));
            // strict < keeps the EARLIEST group attaining the min value
            if (m < bd[k]) { bd[k] = m; gi[k] = j8; }
        }
    }

    // resolve intra-group index of the winner by deterministic recompute
    // (same fmaf expression on the same LDS data -> bitwise identical d),
    // then fold into the global per-query slot via u64 atomicMin.
    const size_t obase = (size_t)(dir * B + b) * Nq;
#pragma unroll
    for (int k = 0; k < QPT; ++k) {
        if (!qv[k]) continue;
        const int g = gi[k];
        float4 f0 = sv[6 * g + 0];
        float4 f1 = sv[6 * g + 1];
        float4 f2 = sv[6 * g + 2];
        float4 f3 = sv[6 * g + 3];
        float4 f4 = sv[6 * g + 4];
        float4 f5 = sv[6 * g + 5];
        float px[8] = { f0.x, f0.w, f1.z, f2.y, f3.x, f3.w, f4.z, f5.y };
        float py[8] = { f0.y, f1.x, f1.w, f2.z, f3.y, f4.x, f4.w, f5.z };
        float pz[8] = { f0.z, f1.y, f2.x, f2.w, f3.z, f4.y, f5.x, f5.w };
        int best = 0;
#pragma unroll
        for (int p = 7; p >= 0; --p) {   // descending: ends at SMALLEST match
            float dx = qx[k] - px[p];
            float dy = qy[k] - py[p];
            float dz = qz[k] - pz[p];
            float d = fmaf(dx, dx, fmaf(dy, dy, dz * dz));
            if (d == bd[k]) best = p;    // match guaranteed (same bits)
        }
        const int idx = base + g * 8 + best;
        // d >= 0 -> float bits order-monotonic as unsigned.
        unsigned long long packed =
            ((unsigned long long)__float_as_uint(bd[k]) << 32) | (unsigned)idx;
        atomicMin(&pp[obase + qi[k]], packed);
    }

    // publish: all threads' device-scope atomicMins are complete at barrier
    // (s_waitcnt vmcnt(0) precedes s_barrier); lane 0 release-increments.
    __syncthreads();
    if (threadIdx.x == 0)
        __hip_atomic_fetch_add(cnt, 1u, __ATOMIC_RELEASE,
                               __HIP_MEMORY_SCOPE_AGENT);
}

extern "C" void kernel_launch(void* const* d_in, const int* in_sizes, int n_in,
                              void* d_out, int out_size, void* d_ws, size_t ws_size,
                              hipStream_t stream) {
    const float* xyz1 = (const float*)d_in[0];
    const float* xyz2 = (const float*)d_in[1];
    float* out = (float*)d_out;
    const int B = 4;
    const int N = in_sizes[0] / (B * 3);
    const int M = in_sizes[1] / (B * 3);
    const int NQ = (N > M ? N : M);
    const int NR = (N > M ? N : M);

    int S = 32;
    while (NR % (S * 8)) S >>= 1;  // need C = NR/S divisible by 8
    const int C = NR / S;

    unsigned long long* pp = (unsigned long long*)d_ws;  // [2][B][NQ] packed
    const int nslots = 2 * B * NQ;
    unsigned* cnt = (unsigned*)(pp + nslots);            // right after pp

    // single memset inits pp slots to ~0ULL AND cnt to 0xFFFFFFFF; finalizers
    // wait for 0xFFFFFFFF + nworkers (unsigned wraparound).
    hipMemsetAsync(pp, 0xFF, (size_t)nslots * 8 + 64, stream);

    const int nqt = (NQ + QPB - 1) / QPB;
    dim3 grid(nqt, B * S + 1, 2);   // +1 y-plane = finalizer blocks
    size_t lds = (size_t)C * 3 * sizeof(float);
    chamfer_main<<<grid, dim3(BLK, 1, 1), lds, stream>>>(
        xyz1, xyz2, pp, cnt, out, N, M, B, S, C);
}

// Round 12
// 129.998 us; speedup vs baseline: 1.0537x; 1.0537x over previous
//
#include <hip/hip_runtime.h>
#include <math.h>

// Chamfer distance, B=4, N=M=8192, fp32.
// Output layout (flat float32): dist1[B*N], dist2[B*M], idx1[B*N] (as float),
// idx2[B*M] (as float).
//
// R11: R9's proven 3-node structure (memset + main + final; R10 proved the
// tail is a fixed ~44us harness floor, per-node cost ~0-2us) with the
// monotone-form inner loop, now WITHOUT R7/R8's poisonous fused-finalize
// epilogue (R8 isolated that poison: exact-form + lastFlag epilogue = 224us).
// Inner: screen on t = |p|^2 - 2 q.p (== d - |q|^2, order-preserving per
// query): u=|p|^2 amortized over 4 queries, 3 fma/eval, fold-min, ~5.4
// inst/eval vs 7.25 exact-form. Correctness: top-2 group-min guard (bd2);
// if bd2-bd < eps=2e-5 (>> ~6e-6 t-rounding bound) -> exact full-chunk
// first-occurrence rescan; else winner group resolved with canonical exact
// d = fmaf(dx,dx,fmaf(dy,dy,dz*dz)). Only exact-d values enter the u64
// atomicMin (dist_bits<<32|idx): min == (min d, tie -> lower idx) ==
// np.argmin first-occurrence.

#define QPT 4         // queries per thread
#define BLK 256       // threads per block
#define QPB (QPT*BLK) // queries per block = 1024

__global__ __launch_bounds__(256, 4) void chamfer_main(
    const float* __restrict__ xyz1, const float* __restrict__ xyz2,
    unsigned long long* __restrict__ pp,
    int N, int M, int B, int S, int C)
{
    const int dir = blockIdx.z;          // 0: xyz1->xyz2, 1: xyz2->xyz1
    const float* q = dir ? xyz2 : xyz1;  // query cloud
    const float* r = dir ? xyz1 : xyz2;  // reference cloud
    const int Nq = dir ? M : N;
    const int Nr = dir ? N : M;
    const int b     = blockIdx.y / S;
    const int split = blockIdx.y % S;
    const int base  = split * C;         // this block's ref-index range [base, base+C)

    extern __shared__ float s[];         // C*3 floats

    // cooperative vectorized tile load (C%8==0 -> byte count divisible by 16)
    {
        const float4* gv = (const float4*)(r + ((size_t)b * Nr + base) * 3);
        float4* sv = (float4*)s;
        const int elems4 = C * 3 / 4;
        for (int t = threadIdx.x; t < elems4; t += BLK) sv[t] = gv[t];
    }
    __syncthreads();

    // load 4 query points; precompute -2q for the monotone form
    float qx[QPT], qy[QPT], qz[QPT];
    float n2x[QPT], n2y[QPT], n2z[QPT];
    int qi[QPT];
    bool qv[QPT];
#pragma unroll
    for (int k = 0; k < QPT; ++k) {
        qi[k] = blockIdx.x * QPB + k * BLK + threadIdx.x;
        qv[k] = qi[k] < Nq;
        const float* qp = q + ((size_t)b * Nq + (qv[k] ? qi[k] : 0)) * 3;
        qx[k] = qp[0]; qy[k] = qp[1]; qz[k] = qp[2];
        n2x[k] = -2.0f * qx[k]; n2y[k] = -2.0f * qy[k]; n2z[k] = -2.0f * qz[k];
    }

    // per-query: best group-min t, its group id, second-best group-min t
    float bd[QPT], bd2[QPT];
    int   gi[QPT];
#pragma unroll
    for (int k = 0; k < QPT; ++k) { bd[k] = INFINITY; bd2[k] = INFINITY; gi[k] = 0; }

    const float4* sv = (const float4*)s;
    const int iters = C / 8;
    for (int j8 = 0; j8 < iters; ++j8) {
        // 24 floats = 8 ref points; all lanes same address -> LDS broadcast
        float4 f0 = sv[6 * j8 + 0];
        float4 f1 = sv[6 * j8 + 1];
        float4 f2 = sv[6 * j8 + 2];
        float4 f3 = sv[6 * j8 + 3];
        float4 f4 = sv[6 * j8 + 4];
        float4 f5 = sv[6 * j8 + 5];
        float px[8] = { f0.x, f0.w, f1.z, f2.y, f3.x, f3.w, f4.z, f5.y };
        float py[8] = { f0.y, f1.x, f1.w, f2.z, f3.y, f4.x, f4.w, f5.z };
        float pz[8] = { f0.z, f1.y, f2.x, f2.w, f3.z, f4.y, f5.x, f5.w };
        // |p|^2 once per point, shared across this thread's 4 queries
        float u[8];
#pragma unroll
        for (int p = 0; p < 8; ++p)
            u[p] = fmaf(pz[p], pz[p], fmaf(py[p], py[p], px[p] * px[p]));
#pragma unroll
        for (int k = 0; k < QPT; ++k) {
            // fold min as we go: two interleaved chains for ILP
            float ma = INFINITY, mb = INFINITY;
#pragma unroll
            for (int p = 0; p < 8; p += 2) {
                float ta = fmaf(n2x[k], px[p],
                           fmaf(n2y[k], py[p],
                           fmaf(n2z[k], pz[p], u[p])));
                float tb = fmaf(n2x[k], px[p + 1],
                           fmaf(n2y[k], py[p + 1],
                           fmaf(n2z[k], pz[p + 1], u[p + 1])));
                ma = fminf(ma, ta);
                mb = fminf(mb, tb);
            }
            float m = fminf(ma, mb);
            float old = bd[k];
            bool c = m < old;                       // strict: earliest group kept
            bd[k]  = c ? m : old;
            gi[k]  = c ? j8 : gi[k];
            bd2[k] = fminf(bd2[k], fmaxf(old, m));  // second-best group-min
        }
    }

    // resolve each query with EXACT d and fold into global slot via atomicMin
    const size_t obase = (size_t)(dir * B + b) * Nq;
    const float eps = 2e-5f;  // ~3x the ~6e-6 worst-case t-rounding bound
#pragma unroll
    for (int k = 0; k < QPT; ++k) {
        if (!qv[k]) continue;
        unsigned long long packed;
        if (bd2[k] - bd[k] < eps) {
            // cross-group ambiguous: exact first-occurrence rescan of chunk
            float best = INFINITY; int bidx = 0;
            for (int j = 0; j < C; ++j) {
                float dx = qx[k] - s[3 * j + 0];
                float dy = qy[k] - s[3 * j + 1];
                float dz = qz[k] - s[3 * j + 2];
                float d = fmaf(dx, dx, fmaf(dy, dy, dz * dz));
                if (d < best) { best = d; bidx = j; }
            }
            packed = ((unsigned long long)__float_as_uint(best) << 32)
                   | (unsigned)(base + bidx);
        } else {
            // winner group unambiguous: resolve its 8 points with exact d
            const int g = gi[k];
            float4 f0 = sv[6 * g + 0];
            float4 f1 = sv[6 * g + 1];
            float4 f2 = sv[6 * g + 2];
            float4 f3 = sv[6 * g + 3];
            float4 f4 = sv[6 * g + 4];
            float4 f5 = sv[6 * g + 5];
            float px[8] = { f0.x, f0.w, f1.z, f2.y, f3.x, f3.w, f4.z, f5.y };
            float py[8] = { f0.y, f1.x, f1.w, f2.z, f3.y, f4.x, f4.w, f5.z };
            float pz[8] = { f0.z, f1.y, f2.x, f2.w, f3.z, f4.y, f5.x, f5.w };
            float d[8];
#pragma unroll
            for (int p = 0; p < 8; ++p) {
                float dx = qx[k] - px[p];
                float dy = qy[k] - py[p];
                float dz = qz[k] - pz[p];
                d[p] = fmaf(dx, dx, fmaf(dy, dy, dz * dz));
            }
            float m = fminf(fminf(fminf(d[0], d[1]), fminf(d[2], d[3])),
                            fminf(fminf(d[4], d[5]), fminf(d[6], d[7])));
            int best = 0;
#pragma unroll
            for (int p = 7; p >= 0; --p)      // descending: smallest match wins
                if (d[p] == m) best = p;      // bitwise match guaranteed
            packed = ((unsigned long long)__float_as_uint(m) << 32)
                   | (unsigned)(base + g * 8 + best);
        }
        atomicMin(&pp[obase + qi[k]], packed);
    }
}

__global__ __launch_bounds__(256) void chamfer_final(
    const unsigned long long* __restrict__ pp,
    float* __restrict__ out, int N, int M, int B)
{
    const int gid = blockIdx.x * blockDim.x + threadIdx.x;
    const int perDir0 = B * N;
    int dir, rem;
    if (gid < perDir0) { dir = 0; rem = gid; }
    else if (gid < perDir0 + B * M) { dir = 1; rem = gid - perDir0; }
    else return;
    const int Nq = dir ? M : N;

    // pp is [2][B][Nq] flat; rem = b*Nq + i
    unsigned long long v = pp[(size_t)(dir * B) * Nq + rem];

    float* dist_out = out + (dir ? (size_t)B * N : 0);
    float* idx_out  = out + (size_t)B * N + (size_t)B * M + (dir ? (size_t)B * N : 0);
    dist_out[rem] = __uint_as_float((unsigned)(v >> 32));
    idx_out[rem]  = (float)(unsigned)(v & 0xffffffffu);
}

extern "C" void kernel_launch(void* const* d_in, const int* in_sizes, int n_in,
                              void* d_out, int out_size, void* d_ws, size_t ws_size,
                              hipStream_t stream) {
    const float* xyz1 = (const float*)d_in[0];
    const float* xyz2 = (const float*)d_in[1];
    float* out = (float*)d_out;
    const int B = 4;
    const int N = in_sizes[0] / (B * 3);
    const int M = in_sizes[1] / (B * 3);
    const int NQ = (N > M ? N : M);
    const int NR = (N > M ? N : M);

    int S = 32;
    while (NR % (S * 8)) S >>= 1;  // need C = NR/S divisible by 8
    const int C = NR / S;

    unsigned long long* pp = (unsigned long long*)d_ws;  // [2][B][NQ] packed slots
    const int nslots = 2 * B * NQ;

    // init pp to ~0ULL via byte-pattern memset (graph-capturable memset node)
    hipMemsetAsync(pp, 0xFF, (size_t)nslots * 8, stream);

    dim3 grid((NQ + QPB - 1) / QPB, B * S, 2);
    size_t lds = (size_t)C * 3 * sizeof(float);
    chamfer_main<<<grid, dim3(BLK, 1, 1), lds, stream>>>(
        xyz1, xyz2, pp, N, M, B, S, C);

    chamfer_final<<<dim3((nslots + 255) / 256, 1, 1), dim3(256, 1, 1), 0, stream>>>(
        pp, out, N, M, B);
}

// Round 13
// 125.572 us; speedup vs baseline: 1.0909x; 1.0353x over previous
//
#include <hip/hip_runtime.h>
#include <math.h>

// Chamfer distance, B=4, N=M=8192, fp32.
// Output layout (flat float32): dist1[B*N], dist2[B*M], idx1[B*N] (as float),
// idx2[B*M] (as float).
//
// R12: packed-FP32 inner loop. gfx950 (FeaturePackedFP32Ops) lowers
// <2 x float> fadd/fmul/fma to v_pk_add/mul/fma_f32 — 2 evals per VALU inst.
// Per-element arithmetic is the EXACT canonical d = fmaf(dx,dx,fmaf(dy,dy,
// dz*dz)) of R6/R9 (IEEE fma per pair lane), so all R6 correctness proofs
// hold unchanged: group-of-8 min tree with strict < keeps the earliest
// group; winner resolved by deterministic scalar recompute (bitwise-identical
// d); descending equality scan -> smallest index; u64 atomicMin of
// (dist_bits<<32|idx) tie-breaks to lower global index == np.argmin
// first-occurrence. absmax 0 expected (measured 0 for this d-form R5-R11).
// LDS tile stored SoA (px/py/pz planes) so ds_read_b128 on a plane yields
// 2 ready v2f pairs with zero shuffle cost. Structure otherwise R9's proven
// 3-node graph (memset-init + main + final).

#define QPT 4         // queries per thread
#define BLK 256       // threads per block
#define QPB (QPT*BLK) // queries per block = 1024

typedef float v2f __attribute__((ext_vector_type(2)));

__global__ __launch_bounds__(256, 4) void chamfer_main(
    const float* __restrict__ xyz1, const float* __restrict__ xyz2,
    unsigned long long* __restrict__ pp,
    int N, int M, int B, int S, int C)
{
    const int dir = blockIdx.z;          // 0: xyz1->xyz2, 1: xyz2->xyz1
    const float* q = dir ? xyz2 : xyz1;  // query cloud
    const float* r = dir ? xyz1 : xyz2;  // reference cloud
    const int Nq = dir ? M : N;
    const int Nr = dir ? N : M;
    const int b     = blockIdx.y / S;
    const int split = blockIdx.y % S;
    const int base  = split * C;         // this block's ref-index range [base, base+C)

    extern __shared__ float s[];         // SoA planes: px[C], py[C], pz[C]

    // staging with AoS->SoA transpose (one-time, 3 scalar loads/thread)
    {
        const float* g = r + ((size_t)b * Nr + base) * 3;
        for (int t = threadIdx.x; t < 3 * C; t += BLK) {
            float v = g[t];
            int pt = t / 3, comp = t - 3 * pt;
            s[comp * C + pt] = v;
        }
    }
    __syncthreads();

    // load 4 query points as v2f splats for packed math
    v2f qxv[QPT], qyv[QPT], qzv[QPT];
    int qi[QPT];
    bool qv[QPT];
#pragma unroll
    for (int k = 0; k < QPT; ++k) {
        qi[k] = blockIdx.x * QPB + k * BLK + threadIdx.x;
        qv[k] = qi[k] < Nq;
        const float* qp = q + ((size_t)b * Nq + (qv[k] ? qi[k] : 0)) * 3;
        qxv[k] = (v2f){qp[0], qp[0]};
        qyv[k] = (v2f){qp[1], qp[1]};
        qzv[k] = (v2f){qp[2], qp[2]};
    }

    // per-query running min + winning 8-group id
    float bd[QPT];
    int   gi[QPT];
#pragma unroll
    for (int k = 0; k < QPT; ++k) { bd[k] = INFINITY; gi[k] = 0; }

    const float4* svx = (const float4*)(s);
    const float4* svy = (const float4*)(s + C);
    const float4* svz = (const float4*)(s + 2 * C);
    const int iters = C / 8;
    for (int j8 = 0; j8 < iters; ++j8) {
        // 8 points = 2 b128 per plane; wave-uniform address -> broadcast
        float4 X0 = svx[2 * j8 + 0], X1 = svx[2 * j8 + 1];
        float4 Y0 = svy[2 * j8 + 0], Y1 = svy[2 * j8 + 1];
        float4 Z0 = svz[2 * j8 + 0], Z1 = svz[2 * j8 + 1];
        // pairs live in aligned register pairs: no shuffles
        v2f xp[4] = { {X0.x, X0.y}, {X0.z, X0.w}, {X1.x, X1.y}, {X1.z, X1.w} };
        v2f yp[4] = { {Y0.x, Y0.y}, {Y0.z, Y0.w}, {Y1.x, Y1.y}, {Y1.z, Y1.w} };
        v2f zp[4] = { {Z0.x, Z0.y}, {Z0.z, Z0.w}, {Z1.x, Z1.y}, {Z1.z, Z1.w} };
#pragma unroll
        for (int k = 0; k < QPT; ++k) {
            v2f d2[4];
#pragma unroll
            for (int i = 0; i < 4; ++i) {
                v2f dx = qxv[k] - xp[i];          // v_pk_add (neg)
                v2f dy = qyv[k] - yp[i];
                v2f dz = qzv[k] - zp[i];
                // exact per-element: fmaf(dx,dx, fmaf(dy,dy, dz*dz))
                d2[i] = __builtin_elementwise_fma(
                            dx, dx, __builtin_elementwise_fma(dy, dy, dz * dz));
            }
            v2f e0 = __builtin_elementwise_min(d2[0], d2[1]);
            v2f e1 = __builtin_elementwise_min(d2[2], d2[3]);
            v2f e  = __builtin_elementwise_min(e0, e1);
            float m = fminf(e.x, e.y);
            // strict < keeps the EARLIEST group attaining the min value
            if (m < bd[k]) { bd[k] = m; gi[k] = j8; }
        }
    }

    // resolve intra-group index by deterministic scalar recompute (bitwise
    // identical to the packed d), then fold via u64 atomicMin.
    const size_t obase = (size_t)(dir * B + b) * Nq;
#pragma unroll
    for (int k = 0; k < QPT; ++k) {
        if (!qv[k]) continue;
        const int g = gi[k];
        float4 X0 = svx[2 * g + 0], X1 = svx[2 * g + 1];
        float4 Y0 = svy[2 * g + 0], Y1 = svy[2 * g + 1];
        float4 Z0 = svz[2 * g + 0], Z1 = svz[2 * g + 1];
        float xs[8] = { X0.x, X0.y, X0.z, X0.w, X1.x, X1.y, X1.z, X1.w };
        float ys[8] = { Y0.x, Y0.y, Y0.z, Y0.w, Y1.x, Y1.y, Y1.z, Y1.w };
        float zs[8] = { Z0.x, Z0.y, Z0.z, Z0.w, Z1.x, Z1.y, Z1.z, Z1.w };
        const float qx = qxv[k].x, qy = qyv[k].x, qz = qzv[k].x;
        int best = 0;
#pragma unroll
        for (int p = 7; p >= 0; --p) {   // descending: ends at SMALLEST match
            float dx = qx - xs[p];
            float dy = qy - ys[p];
            float dz = qz - zs[p];
            float d = fmaf(dx, dx, fmaf(dy, dy, dz * dz));
            if (d == bd[k]) best = p;    // match guaranteed (same bits)
        }
        const int idx = base + g * 8 + best;
        // d >= 0 -> float bits order-monotonic as unsigned.
        unsigned long long packed =
            ((unsigned long long)__float_as_uint(bd[k]) << 32) | (unsigned)idx;
        atomicMin(&pp[obase + qi[k]], packed);
    }
}

__global__ __launch_bounds__(256) void chamfer_final(
    const unsigned long long* __restrict__ pp,
    float* __restrict__ out, int N, int M, int B)
{
    const int gid = blockIdx.x * blockDim.x + threadIdx.x;
    const int perDir0 = B * N;
    int dir, rem;
    if (gid < perDir0) { dir = 0; rem = gid; }
    else if (gid < perDir0 + B * M) { dir = 1; rem = gid - perDir0; }
    else return;
    const int Nq = dir ? M : N;

    // pp is [2][B][Nq] flat; rem = b*Nq + i
    unsigned long long v = pp[(size_t)(dir * B) * Nq + rem];

    float* dist_out = out + (dir ? (size_t)B * N : 0);
    float* idx_out  = out + (size_t)B * N + (size_t)B * M + (dir ? (size_t)B * N : 0);
    dist_out[rem] = __uint_as_float((unsigned)(v >> 32));
    idx_out[rem]  = (float)(unsigned)(v & 0xffffffffu);
}

extern "C" void kernel_launch(void* const* d_in, const int* in_sizes, int n_in,
                              void* d_out, int out_size, void* d_ws, size_t ws_size,
                              hipStream_t stream) {
    const float* xyz1 = (const float*)d_in[0];
    const float* xyz2 = (const float*)d_in[1];
    float* out = (float*)d_out;
    const int B = 4;
    const int N = in_sizes[0] / (B * 3);
    const int M = in_sizes[1] / (B * 3);
    const int NQ = (N > M ? N : M);
    const int NR = (N > M ? N : M);

    int S = 32;
    while (NR % (S * 8)) S >>= 1;  // need C = NR/S divisible by 8
    const int C = NR / S;

    unsigned long long* pp = (unsigned long long*)d_ws;  // [2][B][NQ] packed slots
    const int nslots = 2 * B * NQ;

    // init pp to ~0ULL via byte-pattern memset (graph-capturable memset node)
    hipMemsetAsync(pp, 0xFF, (size_t)nslots * 8, stream);

    dim3 grid((NQ + QPB - 1) / QPB, B * S, 2);
    size_t lds = (size_t)C * 3 * sizeof(float);
    chamfer_main<<<grid, dim3(BLK, 1, 1), lds, stream>>>(
        xyz1, xyz2, pp, N, M, B, S, C);

    chamfer_final<<<dim3((nslots + 255) / 256, 1, 1), dim3(256, 1, 1), 0, stream>>>(
        pp, out, N, M, B);
}